// Round 2
// baseline (255.645 us; speedup 1.0000x reference)
//
#include <hip/hip_runtime.h>

#define POOL 7
#define CCH  256   // channel count (C) — known from the problem

typedef float f32x4 __attribute__((ext_vector_type(4)));

// One wave (64 lanes) per output ROW (box m, py); px=0..6 unrolled inside.
// Each lane handles 4 channels (lane*4 .. lane*4+3) via 16B vector ops.
// 4 waves (4 rows) per 256-thread block.
__global__ __launch_bounds__(256) void roialign_rows(
    const float* __restrict__ boxes,       // [B*N, 4] (y1,x1,y2,x2) normalized
    const int*   __restrict__ image_shape, // [3]
    const float* __restrict__ feat2,       // [B,256,256,C]
    const float* __restrict__ feat3,       // [B,128,128,C]
    const float* __restrict__ feat4,       // [B, 64, 64,C]
    const float* __restrict__ feat5,       // [B, 32, 32,C]
    float*       __restrict__ out,         // [B*N, P, P, C]
    int N, int total_rows)
{
    const int P = POOL;
    const int wave = threadIdx.x >> 6;          // 0..3
    const int lane = threadIdx.x & 63;          // 0..63
    const int task = blockIdx.x * 4 + wave;     // global row id
    if (task >= total_rows) return;

    const int m  = task / P;                    // flat box index in [0, B*N)
    const int py = task - m * P;
    const int b  = m / N;                       // batch index

    // --- box + level (wave-uniform scalar math, once per 7 output points) ---
    const float y1 = boxes[m * 4 + 0];
    const float x1 = boxes[m * 4 + 1];
    const float y2 = boxes[m * 4 + 2];
    const float x2 = boxes[m * 4 + 3];
    const float h  = y2 - y1;
    const float w  = x2 - x1;
    const float area = (float)(image_shape[0] * image_shape[1]);

    // lvl = clip(4 + round(log2(sqrt(w*h)*sqrt(area)/224)), 2, 5); jnp.round == rintf
    const float lvlf = logf(sqrtf(w * h) * sqrtf(area) / 224.0f) * 1.4426950408889634f;
    const int lvl = (int)fminf(fmaxf(4.0f + rintf(lvlf), 2.0f), 5.0f);

    const float* feat;
    int H;
    switch (lvl) {
        case 2:  feat = feat2; H = 256; break;
        case 3:  feat = feat3; H = 128; break;
        case 4:  feat = feat4; H = 64;  break;
        default: feat = feat5; H = 32;  break;
    }
    const int W = H;

    // --- y sample coord + corners (shared by all 7 px) ---
    const float sy = y1 * (float)(H - 1) + (float)py * (h * (float)(H - 1) / (float)(P - 1));
    const float y0f = floorf(sy);
    const float fy  = sy - y0f;
    int yi0 = (int)y0f;
    yi0 = yi0 < 0 ? 0 : (yi0 > H - 1 ? H - 1 : yi0);
    const int yi1 = yi0 + 1 > H - 1 ? H - 1 : yi0 + 1;
    const bool vy = (sy >= 0.0f) && (sy <= (float)(H - 1));

    const int c = lane * 4;                     // C == 256 -> 64 lanes * 4

    const float* __restrict__ fb   = feat + (size_t)b * ((size_t)H * W * CCH);
    const float* __restrict__ row0 = fb + (size_t)yi0 * W * CCH + c;
    const float* __restrict__ row1 = fb + (size_t)yi1 * W * CCH + c;
    float* __restrict__ orow = out + ((size_t)m * (P * P) + (size_t)py * P) * CCH + c;

    const float xbase = x1 * (float)(W - 1);
    const float xstep = w * (float)(W - 1) / (float)(P - 1);
    const float gy = 1.0f - fy;

#pragma unroll
    for (int px = 0; px < P; ++px) {
        const float sx  = xbase + (float)px * xstep;
        const float x0f = floorf(sx);
        const float fx  = sx - x0f;
        int xi0 = (int)x0f;
        xi0 = xi0 < 0 ? 0 : (xi0 > W - 1 ? W - 1 : xi0);
        const int xi1 = xi0 + 1 > W - 1 ? W - 1 : xi0 + 1;
        const bool valid = vy && (sx >= 0.0f) && (sx <= (float)(W - 1));

        // Unconditional clamped loads (always in-bounds) -> branch-free stream
        const f32x4 v00 = *(const f32x4*)(row0 + xi0 * CCH);
        const f32x4 v01 = *(const f32x4*)(row0 + xi1 * CCH);
        const f32x4 v10 = *(const f32x4*)(row1 + xi0 * CCH);
        const f32x4 v11 = *(const f32x4*)(row1 + xi1 * CCH);

        const float gx = 1.0f - fx;
        f32x4 r = (v00 * gx + v01 * fx) * gy + (v10 * gx + v11 * fx) * fy;
        const float vm = valid ? 1.0f : 0.0f;
        r *= vm;

        // Output is write-once, never re-read: bypass L2 to keep it for gathers.
        __builtin_nontemporal_store(r, (f32x4*)(orow + px * CCH));
    }
}

extern "C" void kernel_launch(void* const* d_in, const int* in_sizes, int n_in,
                              void* d_out, int out_size, void* d_ws, size_t ws_size,
                              hipStream_t stream) {
    const float* boxes       = (const float*)d_in[0];  // [B, N, 4]
    const int*   image_shape = (const int*)  d_in[1];  // [3]
    const float* feat2       = (const float*)d_in[2];  // [B,256,256,C]
    const float* feat3       = (const float*)d_in[3];
    const float* feat4       = (const float*)d_in[4];
    const float* feat5       = (const float*)d_in[5];
    float*       out         = (float*)d_out;

    const int B = 2;
    const int N = in_sizes[0] / (B * 4);               // 1000
    const int total_rows = B * N * POOL;               // 14000 row-tasks

    const int rows_per_block = 4;                      // 4 waves/block
    const int grid = (total_rows + rows_per_block - 1) / rows_per_block;

    roialign_rows<<<grid, 256, 0, stream>>>(
        boxes, image_shape, feat2, feat3, feat4, feat5, out,
        N, total_rows);
}